// Round 8
// baseline (792.045 us; speedup 1.0000x reference)
//
#include <hip/hip_runtime.h>
#include <stdint.h>

#define B_  256
#define M_  80
#define T_  1000
#define H_  128
#define G3  384
#define KX  96    // x-side K padded 80 -> 96 (fallback kernel)

typedef _Float16 half8 __attribute__((ext_vector_type(8)));
typedef float    f32x4 __attribute__((ext_vector_type(4)));

#define LOG2E 1.44269504f
#define MFMA(A, Bf, C) __builtin_amdgcn_mfma_f32_16x16x32_f16((A), (Bf), (C), 0, 0, 0)

__device__ __forceinline__ float fast_sigmoid(float v) {
    return __builtin_amdgcn_rcpf(1.0f + __builtin_amdgcn_exp2f(-LOG2E * v));
}
__device__ __forceinline__ float fast_tanh(float v) {
    return fmaf(-2.0f, __builtin_amdgcn_rcpf(1.0f + __builtin_amdgcn_exp2f(2.0f * LOG2E * v)), 1.0f);
}

// ============================================================================
// Pre-pass: gx[b][t][g] = sum_m x[b][m][t] * W_ih[g][m] + b_ih[g]   (f16 out)
// Grid (16, 256): blockIdx.x = 64-row t-window, blockIdx.y = b.
// 256 thr = 4 waves; wave w: N-tiles [6w,6w+6), M-tiles 0..3 (16 t-rows each).
// Dense-M MFMA: A[m=t(lane&15)][k=mel], B[k=mel][n=g(lane&15)].
// ============================================================================
__global__ __launch_bounds__(256) void gx_gemm(
    const float* __restrict__ x, const float* __restrict__ W_ih,
    const float* __restrict__ b_ih, uint16_t* __restrict__ gx)
{
    const int b  = blockIdx.y;
    const int t0 = blockIdx.x * 64;
    const int tid = threadIdx.x;
    const int l = tid & 63, w = tid >> 6;
    const int jn = l & 15, kq = l >> 4;

    const float* xb = x + (size_t)b * M_ * T_;

    half8 bf[6][3];
    float bias[6];
#pragma unroll
    for (int nt = 0; nt < 6; ++nt) {
        const int g = 16 * (6 * w + nt) + jn;
        bias[nt] = b_ih[g];
        const float* wp = W_ih + g * M_;
#pragma unroll
        for (int f = 0; f < 3; ++f)
#pragma unroll
            for (int j = 0; j < 8; ++j) {
                const int k = 32 * f + 8 * kq + j;
                bf[nt][f][j] = (k < M_) ? (_Float16)wp[k] : (_Float16)0.0f;
            }
    }

#pragma unroll
    for (int mt = 0; mt < 4; ++mt) {
        const int tA  = t0 + 16 * mt + jn;            // this lane's A row (t)
        const int tAc = (tA < T_) ? tA : (T_ - 1);    // clamp; stores guarded
        half8 af[3];
#pragma unroll
        for (int f = 0; f < 3; ++f)
#pragma unroll
            for (int j = 0; j < 8; ++j) {
                const int k = 32 * f + 8 * kq + j;
                af[f][j] = (k < M_) ? (_Float16)xb[(size_t)k * T_ + tAc]
                                    : (_Float16)0.0f;
            }

        const int trow = t0 + 16 * mt + 4 * kq;       // D rows: trow + reg
#pragma unroll
        for (int nt = 0; nt < 6; ++nt) {
            f32x4 acc = { bias[nt], bias[nt], bias[nt], bias[nt] };
            acc = MFMA(af[0], bf[nt][0], acc);
            acc = MFMA(af[1], bf[nt][1], acc);
            acc = MFMA(af[2], bf[nt][2], acc);
            const int g = 16 * (6 * w + nt) + jn;
#pragma unroll
            for (int r = 0; r < 4; ++r) {
                const int t = trow + r;
                if (t < T_)
                    gx[((size_t)b * T_ + t) * G3 + g] =
                        __builtin_bit_cast(uint16_t, (_Float16)acc[r]);
            }
        }
    }
}

// ============================================================================
// Recurrence: h-side MFMA only (12/wave/step). gx streamed from d_ws with
// distance-2 prefetch (manual unroll x2). One barrier/step; h double-buffered.
// ============================================================================
__global__ __launch_bounds__(512, 2) void gru_rec(
    const uint16_t* __restrict__ gx, const float* __restrict__ W_hh,
    const float* __restrict__ b_hh, float* __restrict__ out)
{
    const int b = blockIdx.x;
    const int tid = threadIdx.x;
    const int l = tid & 63, w = tid >> 6;
    const int jn = l & 15, kq = l >> 4;
    const int hid = 16 * w + jn;

    __shared__ __align__(16) _Float16 h16[2][H_];

    half8 wr[4], wz[4], wn[4];
#pragma unroll
    for (int f = 0; f < 4; ++f)
#pragma unroll
        for (int j = 0; j < 8; ++j) {
            const int k = 32 * f + 8 * kq + j;
            wr[f][j] = (_Float16)W_hh[(hid)          * H_ + k];
            wz[f][j] = (_Float16)W_hh[(H_ + hid)     * H_ + k];
            wn[f][j] = (_Float16)W_hh[(2 * H_ + hid) * H_ + k];
        }
#pragma unroll
    for (int f = 0; f < 4; ++f) {
        asm volatile("" : "+v"(wr[f]));
        asm volatile("" : "+v"(wz[f]));
        asm volatile("" : "+v"(wn[f]));
    }

    const float bR = b_hh[hid], bZ = b_hh[H_ + hid], bN = b_hh[2 * H_ + hid];
    const uint16_t* gb = gx + (size_t)b * T_ * G3;

    if (tid < H_) h16[0][tid] = (_Float16)0.0f;

    // prefetch slots: (ra,za,na) for even t, (rb,zb,nb2) for odd t
    uint16_t ra = gb[hid],      za = gb[H_ + hid],      na = gb[2 * H_ + hid];
    uint16_t rb = gb[G3 + hid], zb = gb[G3 + H_ + hid], nb2 = gb[G3 + 2 * H_ + hid];

    float h_r = 0.0f;

    for (int t = 0; t < T_; t += 2) {
        // -------- even step (cb=0 -> nb=1), uses slot A, prefetches t+2 ----
        __syncthreads();
        const size_t o2 = (size_t)((t + 2 < T_) ? t + 2 : T_ - 1) * G3;
        const uint16_t rc = gb[o2 + hid], zc = gb[o2 + H_ + hid],
                       nc = gb[o2 + 2 * H_ + hid];
        {
            const int ko = 8 * kq;
            const half8 ah0 = *(const half8*)&h16[0][ko];
            const half8 ah1 = *(const half8*)&h16[0][32 + ko];
            const half8 ah2 = *(const half8*)&h16[0][64 + ko];
            const half8 ah3 = *(const half8*)&h16[0][96 + ko];
            const float vR = (float)__builtin_bit_cast(_Float16, ra) + bR;
            const float vZ = (float)__builtin_bit_cast(_Float16, za) + bZ;
            const float gn = (float)__builtin_bit_cast(_Float16, na);
            f32x4 aR = { vR, vR, vR, vR };
            f32x4 aZ = { vZ, vZ, vZ, vZ };
            f32x4 aN = { bN, bN, bN, bN };
            aR = MFMA(ah0, wr[0], aR); aZ = MFMA(ah0, wz[0], aZ); aN = MFMA(ah0, wn[0], aN);
            aR = MFMA(ah1, wr[1], aR); aZ = MFMA(ah1, wz[1], aZ); aN = MFMA(ah1, wn[1], aN);
            aR = MFMA(ah2, wr[2], aR); aZ = MFMA(ah2, wz[2], aZ); aN = MFMA(ah2, wn[2], aN);
            aR = MFMA(ah3, wr[3], aR); aZ = MFMA(ah3, wz[3], aZ); aN = MFMA(ah3, wn[3], aN);
            const float r  = fast_sigmoid(aR[0]);
            const float z  = fast_sigmoid(aZ[0]);
            const float nv = fast_tanh(fmaf(r, aN[0], gn));
            h_r = fmaf(z, h_r - nv, nv);
            if (l < 16) h16[1][hid] = (_Float16)h_r;
        }
        // -------- odd step (cb=1 -> nb=0), uses slot B, prefetches t+3 -----
        __syncthreads();
        const size_t o3 = (size_t)((t + 3 < T_) ? t + 3 : T_ - 1) * G3;
        const uint16_t rd = gb[o3 + hid], zd = gb[o3 + H_ + hid],
                       nd = gb[o3 + 2 * H_ + hid];
        {
            const int ko = 8 * kq;
            const half8 ah0 = *(const half8*)&h16[1][ko];
            const half8 ah1 = *(const half8*)&h16[1][32 + ko];
            const half8 ah2 = *(const half8*)&h16[1][64 + ko];
            const half8 ah3 = *(const half8*)&h16[1][96 + ko];
            const float vR = (float)__builtin_bit_cast(_Float16, rb) + bR;
            const float vZ = (float)__builtin_bit_cast(_Float16, zb) + bZ;
            const float gn = (float)__builtin_bit_cast(_Float16, nb2);
            f32x4 aR = { vR, vR, vR, vR };
            f32x4 aZ = { vZ, vZ, vZ, vZ };
            f32x4 aN = { bN, bN, bN, bN };
            aR = MFMA(ah0, wr[0], aR); aZ = MFMA(ah0, wz[0], aZ); aN = MFMA(ah0, wn[0], aN);
            aR = MFMA(ah1, wr[1], aR); aZ = MFMA(ah1, wz[1], aZ); aN = MFMA(ah1, wn[1], aN);
            aR = MFMA(ah2, wr[2], aR); aZ = MFMA(ah2, wz[2], aZ); aN = MFMA(ah2, wn[2], aN);
            aR = MFMA(ah3, wr[3], aR); aZ = MFMA(ah3, wz[3], aZ); aN = MFMA(ah3, wn[3], aN);
            const float r  = fast_sigmoid(aR[0]);
            const float z  = fast_sigmoid(aZ[0]);
            const float nv = fast_tanh(fmaf(r, aN[0], gn));
            h_r = fmaf(z, h_r - nv, nv);
            if (l < 16) h16[0][hid] = (_Float16)h_r;
        }
        ra = rc; za = zc; na = nc;
        rb = rd; zb = zd; nb2 = nd;
    }

    if (l < 16) out[(size_t)b * H_ + hid] = h_r;
}

// ============================================================================
// Fallback (R7, verified 656 us): used only if ws_size can't hold gx.
// ============================================================================
__device__ __forceinline__ float wget(const float* __restrict__ W_ih,
                                      const float* __restrict__ W_hh,
                                      int row, int k) {
    if (k < H_) return W_hh[row * H_ + k];
    const int c = k - H_;
    return (c < M_) ? W_ih[row * M_ + c] : 0.0f;
}

__global__ __launch_bounds__(512, 2) void gru_fused(
    const float* __restrict__ x, const float* __restrict__ W_ih,
    const float* __restrict__ W_hh, const float* __restrict__ b_ih,
    const float* __restrict__ b_hh, float* __restrict__ out)
{
    const int b   = blockIdx.x;
    const int tid = threadIdx.x;
    const int l   = tid & 63;
    const int w   = tid >> 6;
    const int jn  = l & 15;
    const int kq  = l >> 4;
    const int hid = w * 16 + jn;

    __shared__ __align__(16) _Float16 h16[2][H_];
    __shared__ __align__(16) _Float16 xs[2][KX];

    half8 wr[7], wz[7], wnh[4], wnx[3];
#pragma unroll
    for (int f = 0; f < 7; ++f)
#pragma unroll
        for (int j = 0; j < 8; ++j) {
            const int k = 32 * f + kq * 8 + j;
            wr[f][j] = (_Float16)wget(W_ih, W_hh, hid,      k);
            wz[f][j] = (_Float16)wget(W_ih, W_hh, H_ + hid, k);
        }
#pragma unroll
    for (int f = 0; f < 4; ++f)
#pragma unroll
        for (int j = 0; j < 8; ++j)
            wnh[f][j] = (_Float16)wget(W_ih, W_hh, 2 * H_ + hid, 32 * f + kq * 8 + j);
#pragma unroll
    for (int f = 0; f < 3; ++f)
#pragma unroll
        for (int j = 0; j < 8; ++j)
            wnx[f][j] = (_Float16)wget(W_ih, W_hh, 2 * H_ + hid, H_ + 32 * f + kq * 8 + j);
#pragma unroll
    for (int f = 0; f < 7; ++f) { asm volatile("" : "+v"(wr[f])); asm volatile("" : "+v"(wz[f])); }
#pragma unroll
    for (int f = 0; f < 4; ++f) asm volatile("" : "+v"(wnh[f]));
#pragma unroll
    for (int f = 0; f < 3; ++f) asm volatile("" : "+v"(wnx[f]));

    const float bR  = b_ih[hid] + b_hh[hid];
    const float bZ  = b_ih[H_ + hid] + b_hh[H_ + hid];
    const float bNX = b_ih[2 * H_ + hid];
    const float bNH = b_hh[2 * H_ + hid];

    const float* xb  = x + (size_t)b * M_ * T_;
    const int    toff = tid * T_;

    if (tid < H_) h16[0][tid] = (_Float16)0.0f;
    if (tid < 2 * KX) ((short*)xs)[tid] = 0;
    if (tid < M_) xs[0][tid] = (_Float16)xb[toff];

    float h_r = 0.0f;

    for (int t = 0; t < T_; ++t) {
        __syncthreads();
        const int cb = t & 1, nb = cb ^ 1;

        float xv = 0.0f;
        const int tn = (t + 1 < T_) ? (t + 1) : (T_ - 1);
        const float* xc = xb + tn;
        if (tid < M_) xv = xc[toff];

        const int ko = kq * 8;
        const half8 ah0 = *(const half8*)&h16[cb][ko];
        const half8 ah1 = *(const half8*)&h16[cb][32 + ko];
        const half8 ah2 = *(const half8*)&h16[cb][64 + ko];
        const half8 ah3 = *(const half8*)&h16[cb][96 + ko];
        const half8 ax0 = *(const half8*)&xs[cb][ko];
        const half8 ax1 = *(const half8*)&xs[cb][32 + ko];
        const half8 ax2 = *(const half8*)&xs[cb][64 + ko];

        f32x4 aR  = { bR,  bR,  bR,  bR  };
        f32x4 aZ  = { bZ,  bZ,  bZ,  bZ  };
        f32x4 aNX = { bNX, bNX, bNX, bNX };
        f32x4 aNH = { bNH, bNH, bNH, bNH };

        aR  = MFMA(ah0, wr[0],  aR);
        aZ  = MFMA(ah0, wz[0],  aZ);
        aNH = MFMA(ah0, wnh[0], aNH);
        aR  = MFMA(ah1, wr[1],  aR);
        aZ  = MFMA(ah1, wz[1],  aZ);
        aNH = MFMA(ah1, wnh[1], aNH);
        aR  = MFMA(ah2, wr[2],  aR);
        aZ  = MFMA(ah2, wz[2],  aZ);
        aNH = MFMA(ah2, wnh[2], aNH);
        aR  = MFMA(ah3, wr[3],  aR);
        aZ  = MFMA(ah3, wz[3],  aZ);
        aNH = MFMA(ah3, wnh[3], aNH);
        aR  = MFMA(ax0, wr[4],  aR);
        aZ  = MFMA(ax0, wz[4],  aZ);
        aNX = MFMA(ax0, wnx[0], aNX);
        aR  = MFMA(ax1, wr[5],  aR);
        aZ  = MFMA(ax1, wz[5],  aZ);
        aNX = MFMA(ax1, wnx[1], aNX);
        aR  = MFMA(ax2, wr[6],  aR);
        aZ  = MFMA(ax2, wz[6],  aZ);
        aNX = MFMA(ax2, wnx[2], aNX);

        if (tid < M_) xs[nb][tid] = (_Float16)xv;

        const float r  = fast_sigmoid(aR[0]);
        const float z  = fast_sigmoid(aZ[0]);
        const float nv = fast_tanh(fmaf(r, aNH[0], aNX[0]));
        h_r = fmaf(z, h_r - nv, nv);
        if (l < 16) h16[nb][hid] = (_Float16)h_r;
    }

    if (l < 16) out[(size_t)b * H_ + hid] = h_r;
}

extern "C" void kernel_launch(void* const* d_in, const int* in_sizes, int n_in,
                              void* d_out, int out_size, void* d_ws, size_t ws_size,
                              hipStream_t stream) {
    const float* x    = (const float*)d_in[0];
    const float* W_ih = (const float*)d_in[1];
    const float* W_hh = (const float*)d_in[2];
    const float* b_ih = (const float*)d_in[3];
    const float* b_hh = (const float*)d_in[4];
    float* out = (float*)d_out;

    const size_t gx_bytes = (size_t)B_ * T_ * G3 * sizeof(uint16_t);
    if (ws_size >= gx_bytes) {
        uint16_t* gx = (uint16_t*)d_ws;
        gx_gemm<<<dim3(16, B_), dim3(256), 0, stream>>>(x, W_ih, b_ih, gx);
        gru_rec<<<dim3(B_), dim3(512), 0, stream>>>(gx, W_hh, b_hh, out);
    } else {
        gru_fused<<<dim3(B_), dim3(512), 0, stream>>>(x, W_ih, W_hh, b_ih, b_hh, out);
    }
}